// Round 14
// baseline (314.785 us; speedup 1.0000x reference)
//
#include <hip/hip_runtime.h>

typedef _Float16 f16x8 __attribute__((ext_vector_type(8)));
typedef float f32x4 __attribute__((ext_vector_type(4)));

__device__ __forceinline__ float h2f(unsigned short h) {
  return (float)__builtin_bit_cast(_Float16, h);
}
__device__ __forceinline__ unsigned short f2h(float f) {
  return __builtin_bit_cast(unsigned short, (_Float16)f);
}

__device__ __forceinline__ void gload_lds16(const void* g, void* l) {
  __builtin_amdgcn_global_load_lds(
      (const __attribute__((address_space(1))) void*)g,
      (__attribute__((address_space(3))) void*)l, 16, 0, 0);
}

// ---------------------------------------------------------------------------
// 128x256 tile GEMM, C = A @ Bt^T (fp16 MFMA, fp32 acc) — r11/r13 proven core:
// single 48KB LDS buffer, 8 waves (2M x 4N), plain syncthreads loop,
// XOR-swizzled LDS (conflict-free ds_read_b128), XCD-swizzled 1D grid.
// A staged fp16 via global_load_lds (measured-best; fp32-A fusion reverted —
// r10-r13 showed a structural ~22us/GEMM penalty for per-lane staging).
// OUTMODE 0: fp32 + bias[col]
//         2: fp16 split-K partial (slice zt), no bias
//         3: fp16 exp(acc+bias), [row][col] + FUSED row-sum -> atomicAdd sums
//         4: fp16 exp(acc+bias), TRANSPOSED ET[col][row] + FUSED col-sum ->
//            atomicAdd sums (shuffle-reduced partials, ~512 atomics/block)
//         5: fp32 acc/sums[row] + bias[col] (fused row-softmax + out; sums raw)
// ---------------------------------------------------------------------------
template <int OUTMODE>
__global__ __launch_bounds__(512, 4) void gemmt(
    const unsigned short* __restrict__ A, const unsigned short* __restrict__ Bt,
    void* __restrict__ Cv, const float* __restrict__ bias,
    float* __restrict__ sums,
    int N, int K, int ldk, int gx, int gy, int nsplit,
    long sA, long sB, long sC)
{
  __shared__ alignas(16) unsigned char smem[49152];  // A 16KB | B 32KB
  const int tid  = threadIdx.x;
  const int lane = tid & 63;
  const int wave = tid >> 6;
  const int waveM = wave >> 2;      // 0..1 (64 rows each)
  const int waveN = wave & 3;       // 0..3 (64 cols each)

  // bijective XCD swizzle (nwg % 8 == 0 for all launches here)
  const int nwg = (int)gridDim.x;
  const int cpx = nwg >> 3;
  const int wg  = (int)blockIdx.x;
  const int w   = (wg & 7) * cpx + (wg >> 3);
  const int x   = w % gx;
  const int rem = w / gx;
  const int y   = rem % gy;
  const int zt  = rem / gy;
  const int bz  = zt / nsplit;
  const int sp  = zt % nsplit;

  const int m0 = y * 128, n0 = x * 256;
  const size_t ldkB = (size_t)ldk * 2;
  const size_t ldkB64 = ldkB * 64, ldkB128 = ldkB * 128;

  // staging addresses (dst linear tid*16 (+8192); src inverse-swizzled)
  const int srow = tid >> 3;                         // 0..63
  const int scol = ((tid * 16) & 127) ^ ((srow & 7) << 4);   // fp16-bytes
  const char* ApR;
  const char* BpR;
  {
    const char* Ab = (const char*)(A + (long)bz * sA + (long)sp * K) + (size_t)m0 * ldkB;
    const char* Bb = (const char*)(Bt + (long)bz * sB + (long)sp * K) + (size_t)n0 * ldkB;
    ApR = Ab + (size_t)srow * ldkB + scol;
    BpR = Bb + (size_t)srow * ldkB + scol;
  }
  const unsigned oA0 = (unsigned)tid * 16;

  // ds_read byte offsets (kk=0); kk=1 offset = kk0 ^ 64 (bits 4-6 swizzle field)
  int offA[4], offB[4];
  {
    const int q16 = (lane >> 4) << 4;
#pragma unroll
    for (int mi = 0; mi < 4; ++mi) {
      const int r = waveM * 64 + mi * 16 + (lane & 15);
      offA[mi] = r * 128 + (q16 ^ ((r & 7) << 4));
    }
#pragma unroll
    for (int ni = 0; ni < 4; ++ni) {
      const int r = waveN * 64 + ni * 16 + (lane & 15);
      offB[ni] = 16384 + r * 128 + (q16 ^ ((r & 7) << 4));
    }
  }

  f32x4 acc[4][4] = {};

  const int nk = K >> 6;
  for (int kt = 0; kt < nk; ++kt) {
    const size_t kb = (size_t)kt * 128;              // fp16 bytes per K-tile
    gload_lds16(ApR + kb,                     smem + oA0);
    gload_lds16(ApR + ldkB64 + kb,            smem + oA0 + 8192);
    gload_lds16(BpR + kb,                     smem + 16384 + oA0);
    gload_lds16(BpR + ldkB64 + kb,            smem + 16384 + oA0 + 8192);
    gload_lds16(BpR + ldkB128 + kb,           smem + 16384 + oA0 + 16384);
    gload_lds16(BpR + ldkB128 + ldkB64 + kb,  smem + 16384 + oA0 + 24576);
    __syncthreads();
#pragma unroll
    for (int kk = 0; kk < 2; ++kk) {
      const int kx = kk << 6;
      f16x8 aF[4], bF[4];
#pragma unroll
      for (int mi = 0; mi < 4; ++mi) aF[mi] = *(const f16x8*)&smem[offA[mi] ^ kx];
#pragma unroll
      for (int ni = 0; ni < 4; ++ni) bF[ni] = *(const f16x8*)&smem[offB[ni] ^ kx];
#pragma unroll
      for (int mi = 0; mi < 4; ++mi)
#pragma unroll
        for (int ni = 0; ni < 4; ++ni)
          acc[mi][ni] = __builtin_amdgcn_mfma_f32_16x16x32_f16(aF[mi], bF[ni], acc[mi][ni], 0, 0, 0);
    }
    __syncthreads();
  }

  // ---- epilogue ----
  const int rb = (lane >> 4) * 4;
  const int cb_ = lane & 15;
  const long zout = (OUTMODE == 2) ? (long)zt : (long)bz;

  if (OUTMODE == 3) {
    // E store + fused row-sums (reduce over cb_ lanes, 4 waveN waves atomic)
#pragma unroll
    for (int m = 0; m < 4; ++m) {
      const int row0 = m0 + waveM * 64 + m * 16 + rb;
      float rs0 = 0, rs1 = 0, rs2 = 0, rs3 = 0;
#pragma unroll
      for (int n = 0; n < 4; ++n) {
        const int col = n0 + waveN * 64 + n * 16 + cb_;
        const float badd = bias[col];
        const float e0 = __expf(acc[m][n][0] + badd);
        const float e1 = __expf(acc[m][n][1] + badd);
        const float e2 = __expf(acc[m][n][2] + badd);
        const float e3 = __expf(acc[m][n][3] + badd);
        unsigned short* C16 = (unsigned short*)Cv;
        C16[zout * sC + (size_t)(row0 + 0) * N + col] = f2h(e0);
        C16[zout * sC + (size_t)(row0 + 1) * N + col] = f2h(e1);
        C16[zout * sC + (size_t)(row0 + 2) * N + col] = f2h(e2);
        C16[zout * sC + (size_t)(row0 + 3) * N + col] = f2h(e3);
        rs0 += e0; rs1 += e1; rs2 += e2; rs3 += e3;
      }
#pragma unroll
      for (int off = 1; off <= 8; off <<= 1) {
        rs0 += __shfl_xor(rs0, off);
        rs1 += __shfl_xor(rs1, off);
        rs2 += __shfl_xor(rs2, off);
        rs3 += __shfl_xor(rs3, off);
      }
      if ((lane & 15) == 0) {
        float* s = sums + (size_t)zout * 4096 + row0;
        atomicAdd(s + 0, rs0);
        atomicAdd(s + 1, rs1);
        atomicAdd(s + 2, rs2);
        atomicAdd(s + 3, rs3);
      }
    }
  } else if (OUTMODE == 4) {
    // transposed E store + fused col-sums (reduce over lane>>4, atomic)
    float cs[4] = {0.f, 0.f, 0.f, 0.f};
#pragma unroll
    for (int m = 0; m < 4; ++m) {
      const int row0 = m0 + waveM * 64 + m * 16 + rb;
#pragma unroll
      for (int n = 0; n < 4; ++n) {
        const int col = n0 + waveN * 64 + n * 16 + cb_;
        const float badd = bias[col];
        unsigned short o4[4];
        float ls = 0.f;
#pragma unroll
        for (int r = 0; r < 4; ++r) {
          const float e = __expf(acc[m][n][r] + badd);
          o4[r] = f2h(e);
          ls += e;
        }
        cs[n] += ls;
        *(uint2*)((unsigned short*)Cv + zout * sC + ((size_t)col << 12) + row0) =
            *(const uint2*)o4;
      }
    }
#pragma unroll
    for (int n = 0; n < 4; ++n) {
      cs[n] += __shfl_xor(cs[n], 16);
      cs[n] += __shfl_xor(cs[n], 32);
    }
    if (lane < 16) {
#pragma unroll
      for (int n = 0; n < 4; ++n) {
        const int col = n0 + waveN * 64 + n * 16 + lane;
        atomicAdd(sums + ((size_t)zout << 10) + col, cs[n]);
      }
    }
  } else {
#pragma unroll
    for (int m = 0; m < 4; ++m) {
      const int row0 = m0 + waveM * 64 + m * 16 + rb;
      float i0 = 0, i1 = 0, i2 = 0, i3 = 0;
      if (OUTMODE == 5) {
        const float4 s4 = *(const float4*)&sums[(size_t)zout * 4096 + row0];
        i0 = 1.0f / s4.x; i1 = 1.0f / s4.y; i2 = 1.0f / s4.z; i3 = 1.0f / s4.w;
      }
#pragma unroll
      for (int n = 0; n < 4; ++n) {
        const int col = n0 + waveN * 64 + n * 16 + cb_;
        if (OUTMODE == 2) {
#pragma unroll
          for (int r = 0; r < 4; ++r)
            ((unsigned short*)Cv)[zout * sC + (size_t)(row0 + r) * N + col] = f2h(acc[m][n][r]);
        } else if (OUTMODE == 5) {
          const float badd = bias[col];
          float* C32 = (float*)Cv;
          C32[zout * sC + (size_t)(row0 + 0) * N + col] = acc[m][n][0] * i0 + badd;
          C32[zout * sC + (size_t)(row0 + 1) * N + col] = acc[m][n][1] * i1 + badd;
          C32[zout * sC + (size_t)(row0 + 2) * N + col] = acc[m][n][2] * i2 + badd;
          C32[zout * sC + (size_t)(row0 + 3) * N + col] = acc[m][n][3] * i3 + badd;
        } else {
          const float badd = bias[col];
#pragma unroll
          for (int r = 0; r < 4; ++r)
            ((float*)Cv)[zout * sC + (size_t)(row0 + r) * N + col] = acc[m][n][r] + badd;
        }
      }
    }
  }
}

// ---------------------------------------------------------------------------
// fp32 -> fp16 convert, one input selected by blockIdx.y (q,k,v)
// ---------------------------------------------------------------------------
__global__ __launch_bounds__(256) void conv_h(
    const float* __restrict__ in, unsigned short* __restrict__ out)
{
  const int i = blockIdx.x * 256 + threadIdx.x;   // 4M float4 groups
  float4 v = ((const float4*)in)[i];
  unsigned short o4[4] = {f2h(v.x), f2h(v.y), f2h(v.z), f2h(v.w)};
  ((uint2*)out)[i] = *(const uint2*)o4;
}

// ---------------------------------------------------------------------------
// Weight transpose + fp16 (4 weights in one launch, z selects):
// WT[z][c][r] = f16(W_z[r][c]), each 1024x1024
// ---------------------------------------------------------------------------
__global__ __launch_bounds__(256) void w_trh4(
    const float* __restrict__ W0, const float* __restrict__ W1,
    const float* __restrict__ W2, const float* __restrict__ W3,
    unsigned short* __restrict__ WTb)
{
  __shared__ unsigned short tile[64][73];
  const int z = blockIdx.z;
  const float* W = (z == 0) ? W0 : (z == 1) ? W1 : (z == 2) ? W2 : W3;
  unsigned short* WT = WTb + (size_t)z * 1024 * 1024;
  const int c0 = blockIdx.x * 64;
  const int r0 = blockIdx.y * 64;
  const int tid = threadIdx.x;
  const int r = tid >> 2;
  const int cq = (tid & 3) * 16;
#pragma unroll
  for (int i = 0; i < 4; ++i) {
    const int c = cq + i * 4;
    const float4 v = *(const float4*)&W[(size_t)(r0 + r) * 1024 + c0 + c];
    tile[r][c + 0] = f2h(v.x);
    tile[r][c + 1] = f2h(v.y);
    tile[r][c + 2] = f2h(v.z);
    tile[r][c + 3] = f2h(v.w);
  }
  __syncthreads();
  const int c = tid >> 2;
  const int rq = (tid & 3) * 16;
  unsigned short outv[16];
#pragma unroll
  for (int j = 0; j < 16; ++j) outv[j] = tile[rq + j][c];
  unsigned short* Tb = WT + (size_t)(c0 + c) * 1024 + r0 + rq;
  ((uint4*)Tb)[0] = ((const uint4*)outv)[0];
  ((uint4*)Tb)[1] = ((const uint4*)outv)[1];
}

// ---------------------------------------------------------------------------
// split-K x4 reduce of fp16 partials with diag scaling from RAW sums:
// O[b][dk][dv] = f16( (sum_s P[..]) / skr[b][dk] / svr[b][dv] )
// ---------------------------------------------------------------------------
__global__ __launch_bounds__(256) void red4m(
    const unsigned short* __restrict__ P, const float* __restrict__ skr,
    const float* __restrict__ svr, unsigned short* __restrict__ O)
{
  const int i = blockIdx.x * 256 + threadIdx.x;   // 2^20 groups of 4
  const int b = i >> 18;
  const int j = i & 262143;
  const int dk = j >> 8;
  const int dv0 = (j & 255) << 2;
  float s0 = 0, s1 = 0, s2 = 0, s3 = 0;
#pragma unroll
  for (int sl = 0; sl < 4; ++sl) {
    const uint2 u = *(const uint2*)(P + (((long)(b * 4 + sl)) << 20) + ((long)j << 2));
    s0 += h2f(u.x & 0xffff); s1 += h2f(u.x >> 16);
    s2 += h2f(u.y & 0xffff); s3 += h2f(u.y >> 16);
  }
  const float fk = 1.0f / skr[(b << 10) + dk];
  const float4 fvr = *(const float4*)&svr[(b << 10) + dv0];
  unsigned short o4[4] = {f2h(s0 * fk / fvr.x), f2h(s1 * fk / fvr.y),
                          f2h(s2 * fk / fvr.z), f2h(s3 * fk / fvr.w)};
  *(uint2*)(O + ((long)b << 20) + ((long)j << 2)) = *(const uint2*)o4;
}

// ---------------------------------------------------------------------------
// split-K x4 reduce, plain: O[b][i] = f16(sum_s P[b*4+s][i])
// ---------------------------------------------------------------------------
__global__ __launch_bounds__(256) void red4h(
    const unsigned short* __restrict__ P, unsigned short* __restrict__ O)
{
  const int i = blockIdx.x * 256 + threadIdx.x;
  const int b = i >> 18;
  const int j = i & 262143;
  float s0 = 0, s1 = 0, s2 = 0, s3 = 0;
#pragma unroll
  for (int sl = 0; sl < 4; ++sl) {
    const uint2 u = *(const uint2*)(P + (((long)(b * 4 + sl)) << 20) + ((long)j << 2));
    s0 += h2f(u.x & 0xffff); s1 += h2f(u.x >> 16);
    s2 += h2f(u.y & 0xffff); s3 += h2f(u.y >> 16);
  }
  unsigned short o4[4] = {f2h(s0), f2h(s1), f2h(s2), f2h(s3)};
  *(uint2*)(O + ((long)b << 20) + ((long)j << 2)) = *(const uint2*)o4;
}

// ---------------------------------------------------------------------------
extern "C" void kernel_launch(void* const* d_in, const int* in_sizes, int n_in,
                              void* d_out, int out_size, void* d_ws, size_t ws_size,
                              hipStream_t stream) {
  const float* q  = (const float*)d_in[0];
  const float* k  = (const float*)d_in[1];
  const float* v  = (const float*)d_in[2];
  const float* Wq = (const float*)d_in[3];
  const float* bq = (const float*)d_in[4];
  const float* Wk = (const float*)d_in[5];
  const float* bk = (const float*)d_in[6];
  const float* Wv = (const float*)d_in[7];
  const float* bv = (const float*)d_in[8];
  const float* Wo = (const float*)d_in[9];
  const float* bo = (const float*)d_in[10];
  float* out = (float*)d_out;

  // workspace layout (~150 MB); Xh aliases Part (Xh dead before Part written)
  char* p = (char*)d_ws;
  unsigned short* Part = (unsigned short*)p; p += 33554432;   // fp16 [16][1024][1024]
  unsigned short* Xh = Part;                                  // fp16 [16384][1024] alias
  unsigned short* WTb = (unsigned short*)p;  p += 8388608;    // 4x fp16 [1024][1024]
  unsigned short* WqT = WTb;
  unsigned short* WkT = WTb + 1L * 1024 * 1024;
  unsigned short* WvT = WTb + 2L * 1024 * 1024;
  unsigned short* WoT = WTb + 3L * 1024 * 1024;
  unsigned short* Eq  = (unsigned short*)p;  p += 33554432;   // fp16 [4][4096][1024]
  unsigned short* ETk = (unsigned short*)p;  p += 33554432;   // fp16 [4][1024][4096]
  unsigned short* ETv = (unsigned short*)p;  p += 33554432;
  unsigned short* Mh  = (unsigned short*)p;  p += 8388608;    // fp16 [4][1024][1024]
  unsigned short* GTh = (unsigned short*)p;  p += 8388608;    // fp16 [4][1024][1024]
  float* sqraw = (float*)p; p += 16384 * 4;   // raw row-sums of Eq
  float* skraw = (float*)p; p += 4096 * 4;    // raw col-sums of Ek
  float* svraw = (float*)p; p += 4096 * 4;    // raw col-sums of Ev

  const dim3 blk(256);
  const dim3 blk512(512);
  const long S22 = 4096L * 1024;   // 2^22
  const long S20 = 1024L * 1024;   // 2^20

  // zero the atomic sum accumulators (96 KB; graph-capturable)
  hipMemsetAsync(sqraw, 0, (16384 + 4096 + 4096) * sizeof(float), stream);

  // weights -> fp16 transposed (one launch)
  w_trh4<<<dim3(16, 16, 4), blk, 0, stream>>>(Wq, Wk, Wv, Wo, WTb);

  // ---- Q path: Eq = exp(q@Wq + bq) + fused row-sums -> sqraw
  conv_h<<<16384, blk, 0, stream>>>(q, Xh);
  gemmt<3><<<512, blk512, 0, stream>>>(Xh, WqT, Eq, bq, sqraw,
      1024, 1024, 1024, 4, 32, 1, S22, 0, S22);

  // ---- K path: ETk[b][d][l] = exp(k@Wk + bk)^T + fused col-sums -> skraw
  conv_h<<<16384, blk, 0, stream>>>(k, Xh);
  gemmt<4><<<512, blk512, 0, stream>>>(Xh, WkT, ETk, bk, skraw,
      1024, 1024, 1024, 4, 32, 1, S22, 0, S22);

  // ---- V path
  conv_h<<<16384, blk, 0, stream>>>(v, Xh);
  gemmt<4><<<512, blk512, 0, stream>>>(Xh, WvT, ETv, bv, svraw,
      1024, 1024, 1024, 4, 32, 1, S22, 0, S22);

  // ---- Mraw partials: P[b*4+s] = ETk_chunk @ ETv_chunk^T (K=4096 split x4)
  //      Mh = f16(red4(P) / skraw[dk] / svraw[dv])
  gemmt<2><<<512, blk512, 0, stream>>>(ETk, ETv, Part, nullptr, nullptr,
      1024, 1024, 4096, 4, 8, 4, S22, S22, S20);
  red4m<<<4096, blk, 0, stream>>>(Part, skraw, svraw, Mh);

  // ---- GT_b = (M_b @ Wo)^T = WoT @ M_b^T : K=1024 split x4
  gemmt<2><<<512, blk512, 0, stream>>>(WoT, Mh, Part, nullptr, nullptr,
      1024, 256, 1024, 4, 8, 4, 0, S20, S20);
  red4h<<<4096, blk, 0, stream>>>(Part, GTh);

  // ---- Out_b = diag(1/sqraw) * (Eq_b @ GT_b^T) + bo
  gemmt<5><<<512, blk512, 0, stream>>>(Eq, GTh, out, bo, sqraw,
      1024, 1024, 1024, 4, 32, 1, S22, S20, S22);

  (void)in_sizes; (void)n_in; (void)out_size; (void)ws_size;
}

// Round 15
// 280.853 us; speedup vs baseline: 1.1208x; 1.1208x over previous
//
#include <hip/hip_runtime.h>

typedef _Float16 f16x8 __attribute__((ext_vector_type(8)));
typedef float f32x4 __attribute__((ext_vector_type(4)));
typedef long lx2 __attribute__((ext_vector_type(2)));

__device__ __forceinline__ float h2f(unsigned short h) {
  return (float)__builtin_bit_cast(_Float16, h);
}
__device__ __forceinline__ unsigned short f2h(float f) {
  return __builtin_bit_cast(unsigned short, (_Float16)f);
}
// fp32 -> OCP e4m3fn: RNE, saturating, subnormal-correct (via fp16 bits)
__device__ __forceinline__ unsigned char f2e4(float f) {
  unsigned short h = __builtin_bit_cast(unsigned short, (_Float16)f);
  unsigned s = (h >> 8) & 0x80u;
  unsigned ae = h & 0x7FFFu;
  if (ae >= 0x5F00u) return (unsigned char)(s | 0x7Eu);   // >=448 clamp
  if (ae >= 0x2400u) {                                    // >= 2^-6: normal
    unsigned t = ae - 0x2000u;                            // rebias exp
    t = (t + 0x3Fu + ((t >> 7) & 1u)) >> 7;               // RNE drop 7 bits
    return (unsigned char)(s | t);
  }
  // subnormal: n = RNE(value * 2^9), n in [0,8]; n==8 == min normal encoding
  float v = (float)__builtin_bit_cast(_Float16, (unsigned short)ae) * 512.0f;
  int n = (int)rintf(v);
  return (unsigned char)(s | (unsigned)n);
}
__device__ __forceinline__ unsigned pk4e4(float a, float b, float c, float d) {
  return (unsigned)f2e4(a) | ((unsigned)f2e4(b) << 8) |
         ((unsigned)f2e4(c) << 16) | ((unsigned)f2e4(d) << 24);
}

__device__ __forceinline__ void gload_lds16(const void* g, void* l) {
  __builtin_amdgcn_global_load_lds(
      (const __attribute__((address_space(1))) void*)g,
      (__attribute__((address_space(3))) void*)l, 16, 0, 0);
}

// ---------------------------------------------------------------------------
// 128x256 tile GEMM, C = A @ Bt^T (fp32 acc) — r13 proven core: single 48KB
// LDS buffer, 8 waves (2Mx4N), plain syncthreads loop, XOR-swizzled LDS,
// XCD-swizzled 1D grid.
// DT 0: fp16 operands (BK=64, mfma_f16).  DT 1: fp8 e4m3 (BK=128, 2x
//   mfma_fp8_fp8 per 16B fragment; byte addressing identical — k-permutation
//   k = kx+16g+j consistent across A/B so C is exact).
// ASRC 0: A staged via global_load_lds (element size per DT).
// ASRC 1 (DT=0 only): A fp32, T14 reg-prefetch + cvt + ds_write.
// OUTMODE 0: fp32 + bias[col]
//         2: fp16 split-K partial (slice zt)
//         3: fp8(e/16), e=exp(acc+bias), [row][col] + fused row-sums (raw e)
//         4: fp8(e/16) TRANSPOSED ET[col][row] packed 4B + fused col-sums
//         5: fp32 acc/(256*sums[row]) + bias[col]  (fp8-chain final scale)
// ---------------------------------------------------------------------------
template <int DT, int ASRC, int OUTMODE>
__global__ __launch_bounds__(512, 4) void gemmt(
    const void* __restrict__ Av, const void* __restrict__ Btv,
    void* __restrict__ Cv, const float* __restrict__ bias,
    float* __restrict__ sums,
    int N, int K, int ldk, int gx, int gy, int nsplit,
    long sA, long sB, long sC)
{
  __shared__ alignas(16) unsigned char smem[49152];  // A 16KB | B 32KB
  const int tid  = threadIdx.x;
  const int lane = tid & 63;
  const int wave = tid >> 6;
  const int waveM = wave >> 2;
  const int waveN = wave & 3;
  const int EB = (DT == 1) ? 1 : 2;                  // operand element bytes

  // bijective XCD swizzle (nwg % 8 == 0 for all launches here)
  const int nwg = (int)gridDim.x;
  const int cpx = nwg >> 3;
  const int wg  = (int)blockIdx.x;
  const int w   = (wg & 7) * cpx + (wg >> 3);
  const int x   = w % gx;
  const int rem = w / gx;
  const int y   = rem % gy;
  const int zt  = rem / gy;
  const int bz  = zt / nsplit;
  const int sp  = zt % nsplit;

  const int m0 = y * 128, n0 = x * 256;
  const size_t ldkB = (size_t)ldk * EB;
  const size_t ldkB64 = ldkB * 64, ldkB128 = ldkB * 128;

  // staging addresses (dst linear tid*16; src inverse-swizzled, byte domain)
  const int srow = tid >> 3;                         // 0..63
  const int scol = ((tid * 16) & 127) ^ ((srow & 7) << 4);
  const char* ApR16 = nullptr;
  const char* ApR32 = nullptr;
  const char* BpR;
  {
    const char* Bb = (const char*)Btv + ((long)bz * sB + (long)sp * K) * EB
                     + (size_t)n0 * ldkB;
    BpR = Bb + (size_t)srow * ldkB + scol;
    if (ASRC == 0) {
      const char* Ab = (const char*)Av + ((long)bz * sA + (long)sp * K) * EB
                       + (size_t)m0 * ldkB;
      ApR16 = Ab + (size_t)srow * ldkB + scol;
    } else {
      const char* Ab = (const char*)Av + ((long)bz * sA + (long)sp * K) * 4
                       + (size_t)m0 * (size_t)ldk * 4;
      ApR32 = Ab + (size_t)srow * (size_t)ldk * 4 + (size_t)scol * 2;
    }
  }
  const unsigned oA0 = (unsigned)tid * 16;
  const size_t ldk32_64 = (size_t)ldk * 4 * 64;

  // fragment byte offsets (kk=0); kk=1 is ^64 (swizzle field = bits 4-6)
  int offA[4], offB[4];
  {
    const int q16 = (lane >> 4) << 4;
#pragma unroll
    for (int mi = 0; mi < 4; ++mi) {
      const int r = waveM * 64 + mi * 16 + (lane & 15);
      offA[mi] = r * 128 + (q16 ^ ((r & 7) << 4));
    }
#pragma unroll
    for (int ni = 0; ni < 4; ++ni) {
      const int r = waveN * 64 + ni * 16 + (lane & 15);
      offB[ni] = 16384 + r * 128 + (q16 ^ ((r & 7) << 4));
    }
  }

  f32x4 acc[4][4] = {};

  // T14 prefetch registers (ASRC==1)
  float4 pf0, pf1, pf2, pf3;
  if (ASRC == 1) {
    const char* s0 = ApR32;
    const char* s1 = s0 + ldk32_64;
    pf0 = *(const float4*)s0;  pf1 = *(const float4*)(s0 + 16);
    pf2 = *(const float4*)s1;  pf3 = *(const float4*)(s1 + 16);
  }

  const int nk = (DT == 1) ? (K >> 7) : (K >> 6);    // 128B of k per tile
  for (int kt = 0; kt < nk; ++kt) {
    const size_t kb = (size_t)kt * 128;              // bytes per K-tile
    if (ASRC == 0) {
      gload_lds16(ApR16 + kb,           smem + oA0);
      gload_lds16(ApR16 + ldkB64 + kb,  smem + oA0 + 8192);
    } else {
      unsigned short h0[8], h1[8];
      const float* fa0 = (const float*)&pf0; const float* fa1 = (const float*)&pf1;
      const float* fb0 = (const float*)&pf2; const float* fb1 = (const float*)&pf3;
#pragma unroll
      for (int e = 0; e < 4; ++e) {
        h0[e] = f2h(fa0[e]); h0[4 + e] = f2h(fa1[e]);
        h1[e] = f2h(fb0[e]); h1[4 + e] = f2h(fb1[e]);
      }
      *(uint4*)&smem[oA0]        = *(const uint4*)h0;
      *(uint4*)&smem[oA0 + 8192] = *(const uint4*)h1;
      if (kt + 1 < nk) {
        const char* s0 = ApR32 + (size_t)(kt + 1) * 256;
        const char* s1 = s0 + ldk32_64;
        pf0 = *(const float4*)s0;  pf1 = *(const float4*)(s0 + 16);
        pf2 = *(const float4*)s1;  pf3 = *(const float4*)(s1 + 16);
      }
    }
    gload_lds16(BpR + kb,                     smem + 16384 + oA0);
    gload_lds16(BpR + ldkB64 + kb,            smem + 16384 + oA0 + 8192);
    gload_lds16(BpR + ldkB128 + kb,           smem + 16384 + oA0 + 16384);
    gload_lds16(BpR + ldkB128 + ldkB64 + kb,  smem + 16384 + oA0 + 24576);
    __syncthreads();
#pragma unroll
    for (int kk = 0; kk < 2; ++kk) {
      const int kx = kk << 6;
      if (DT == 0) {
        f16x8 aF[4], bF[4];
#pragma unroll
        for (int mi = 0; mi < 4; ++mi) aF[mi] = *(const f16x8*)&smem[offA[mi] ^ kx];
#pragma unroll
        for (int ni = 0; ni < 4; ++ni) bF[ni] = *(const f16x8*)&smem[offB[ni] ^ kx];
#pragma unroll
        for (int mi = 0; mi < 4; ++mi)
#pragma unroll
          for (int ni = 0; ni < 4; ++ni)
            acc[mi][ni] = __builtin_amdgcn_mfma_f32_16x16x32_f16(aF[mi], bF[ni], acc[mi][ni], 0, 0, 0);
      } else {
        lx2 aF[4], bF[4];
#pragma unroll
        for (int mi = 0; mi < 4; ++mi) aF[mi] = *(const lx2*)&smem[offA[mi] ^ kx];
#pragma unroll
        for (int ni = 0; ni < 4; ++ni) bF[ni] = *(const lx2*)&smem[offB[ni] ^ kx];
#pragma unroll
        for (int h = 0; h < 2; ++h)
#pragma unroll
          for (int mi = 0; mi < 4; ++mi)
#pragma unroll
            for (int ni = 0; ni < 4; ++ni)
              acc[mi][ni] = __builtin_amdgcn_mfma_f32_16x16x32_fp8_fp8(
                  aF[mi][h], bF[ni][h], acc[mi][ni], 0, 0, 0);
      }
    }
    __syncthreads();
  }

  // ---- epilogue ----
  const int rb = (lane >> 4) * 4;
  const int cb_ = lane & 15;
  const long zout = (OUTMODE == 2) ? (long)zt : (long)bz;

  if (OUTMODE == 3) {
    // fp8(e/16) store [row][col] + fused row-sums of raw e
#pragma unroll
    for (int m = 0; m < 4; ++m) {
      const int row0 = m0 + waveM * 64 + m * 16 + rb;
      float rs0 = 0, rs1 = 0, rs2 = 0, rs3 = 0;
#pragma unroll
      for (int n = 0; n < 4; ++n) {
        const int col = n0 + waveN * 64 + n * 16 + cb_;
        const float badd = bias[col];
        const float e0 = __expf(acc[m][n][0] + badd);
        const float e1 = __expf(acc[m][n][1] + badd);
        const float e2 = __expf(acc[m][n][2] + badd);
        const float e3 = __expf(acc[m][n][3] + badd);
        unsigned char* C8 = (unsigned char*)Cv + zout * sC;
        C8[(size_t)(row0 + 0) * N + col] = f2e4(e0 * 0.0625f);
        C8[(size_t)(row0 + 1) * N + col] = f2e4(e1 * 0.0625f);
        C8[(size_t)(row0 + 2) * N + col] = f2e4(e2 * 0.0625f);
        C8[(size_t)(row0 + 3) * N + col] = f2e4(e3 * 0.0625f);
        rs0 += e0; rs1 += e1; rs2 += e2; rs3 += e3;
      }
#pragma unroll
      for (int off = 1; off <= 8; off <<= 1) {
        rs0 += __shfl_xor(rs0, off);
        rs1 += __shfl_xor(rs1, off);
        rs2 += __shfl_xor(rs2, off);
        rs3 += __shfl_xor(rs3, off);
      }
      if ((lane & 15) == 0) {
        float* s = sums + (size_t)zout * 4096 + row0;
        atomicAdd(s + 0, rs0);
        atomicAdd(s + 1, rs1);
        atomicAdd(s + 2, rs2);
        atomicAdd(s + 3, rs3);
      }
    }
  } else if (OUTMODE == 4) {
    // transposed fp8(e/16) store (packed 4B) + fused col-sums of raw e
    float cs[4] = {0.f, 0.f, 0.f, 0.f};
#pragma unroll
    for (int m = 0; m < 4; ++m) {
      const int row0 = m0 + waveM * 64 + m * 16 + rb;
#pragma unroll
      for (int n = 0; n < 4; ++n) {
        const int col = n0 + waveN * 64 + n * 16 + cb_;
        const float badd = bias[col];
        float ev[4];
        float ls = 0.f;
#pragma unroll
        for (int r = 0; r < 4; ++r) {
          ev[r] = __expf(acc[m][n][r] + badd);
          ls += ev[r];
        }
        cs[n] += ls;
        *(unsigned*)((unsigned char*)Cv + zout * sC + ((size_t)col << 12) + row0) =
            pk4e4(ev[0] * 0.0625f, ev[1] * 0.0625f, ev[2] * 0.0625f, ev[3] * 0.0625f);
      }
    }
#pragma unroll
    for (int n = 0; n < 4; ++n) {
      cs[n] += __shfl_xor(cs[n], 16);
      cs[n] += __shfl_xor(cs[n], 32);
    }
    if (lane < 16) {
#pragma unroll
      for (int n = 0; n < 4; ++n) {
        const int col = n0 + waveN * 64 + n * 16 + lane;
        atomicAdd(sums + ((size_t)zout << 10) + col, cs[n]);
      }
    }
  } else {
#pragma unroll
    for (int m = 0; m < 4; ++m) {
      const int row0 = m0 + waveM * 64 + m * 16 + rb;
      float i0 = 0, i1 = 0, i2 = 0, i3 = 0;
      if (OUTMODE == 5) {
        const float4 s4 = *(const float4*)&sums[(size_t)zout * 4096 + row0];
        i0 = 1.0f / (256.0f * s4.x); i1 = 1.0f / (256.0f * s4.y);
        i2 = 1.0f / (256.0f * s4.z); i3 = 1.0f / (256.0f * s4.w);
      }
#pragma unroll
      for (int n = 0; n < 4; ++n) {
        const int col = n0 + waveN * 64 + n * 16 + cb_;
        if (OUTMODE == 2) {
#pragma unroll
          for (int r = 0; r < 4; ++r)
            ((unsigned short*)Cv)[zout * sC + (size_t)(row0 + r) * N + col] = f2h(acc[m][n][r]);
        } else if (OUTMODE == 5) {
          const float badd = bias[col];
          float* C32 = (float*)Cv;
          C32[zout * sC + (size_t)(row0 + 0) * N + col] = acc[m][n][0] * i0 + badd;
          C32[zout * sC + (size_t)(row0 + 1) * N + col] = acc[m][n][1] * i1 + badd;
          C32[zout * sC + (size_t)(row0 + 2) * N + col] = acc[m][n][2] * i2 + badd;
          C32[zout * sC + (size_t)(row0 + 3) * N + col] = acc[m][n][3] * i3 + badd;
        } else {
          const float badd = bias[col];
#pragma unroll
          for (int r = 0; r < 4; ++r)
            ((float*)Cv)[zout * sC + (size_t)(row0 + r) * N + col] = acc[m][n][r] + badd;
        }
      }
    }
  }
}

// ---------------------------------------------------------------------------
// Weight transpose + fp16 (4 weights, z selects): WT[z][c][r] = f16(W_z[r][c])
// ---------------------------------------------------------------------------
__global__ __launch_bounds__(256) void w_trh4(
    const float* __restrict__ W0, const float* __restrict__ W1,
    const float* __restrict__ W2, const float* __restrict__ W3,
    unsigned short* __restrict__ WTb)
{
  __shared__ unsigned short tile[64][73];
  const int z = blockIdx.z;
  const float* W = (z == 0) ? W0 : (z == 1) ? W1 : (z == 2) ? W2 : W3;
  unsigned short* WT = WTb + (size_t)z * 1024 * 1024;
  const int c0 = blockIdx.x * 64;
  const int r0 = blockIdx.y * 64;
  const int tid = threadIdx.x;
  const int r = tid >> 2;
  const int cq = (tid & 3) * 16;
#pragma unroll
  for (int i = 0; i < 4; ++i) {
    const int c = cq + i * 4;
    const float4 v = *(const float4*)&W[(size_t)(r0 + r) * 1024 + c0 + c];
    tile[r][c + 0] = f2h(v.x);
    tile[r][c + 1] = f2h(v.y);
    tile[r][c + 2] = f2h(v.z);
    tile[r][c + 3] = f2h(v.w);
  }
  __syncthreads();
  const int c = tid >> 2;
  const int rq = (tid & 3) * 16;
  unsigned short outv[16];
#pragma unroll
  for (int j = 0; j < 16; ++j) outv[j] = tile[rq + j][c];
  unsigned short* Tb = WT + (size_t)(c0 + c) * 1024 + r0 + rq;
  ((uint4*)Tb)[0] = ((const uint4*)outv)[0];
  ((uint4*)Tb)[1] = ((const uint4*)outv)[1];
}

// ---------------------------------------------------------------------------
// WoT8[i] = fp8(WoT[i] * 8)   (1M elems, 4/thread)
// ---------------------------------------------------------------------------
__global__ __launch_bounds__(256) void wo8k(
    const unsigned short* __restrict__ WoT, unsigned char* __restrict__ WoT8)
{
  const int i = blockIdx.x * 256 + threadIdx.x;   // 262144 groups of 4
  const uint2 u = ((const uint2*)WoT)[i];
  ((unsigned*)WoT8)[i] = pk4e4(h2f(u.x & 0xffff) * 8.f, h2f(u.x >> 16) * 8.f,
                               h2f(u.y & 0xffff) * 8.f, h2f(u.y >> 16) * 8.f);
}

// ---------------------------------------------------------------------------
// split-K x4 reduce of fp16 partials -> fp8 M with normalization:
// M8[b][dk][dv] = f8( sum * 2^22 / (skr[b][dk] * svr[b][dv]) )
// ---------------------------------------------------------------------------
__global__ __launch_bounds__(256) void red4m(
    const unsigned short* __restrict__ P, const float* __restrict__ skr,
    const float* __restrict__ svr, unsigned char* __restrict__ O)
{
  const int i = blockIdx.x * 256 + threadIdx.x;   // 2^20 groups of 4
  const int b = i >> 18;
  const int j = i & 262143;
  const int dk = j >> 8;
  const int dv0 = (j & 255) << 2;
  float s0 = 0, s1 = 0, s2 = 0, s3 = 0;
#pragma unroll
  for (int sl = 0; sl < 4; ++sl) {
    const uint2 u = *(const uint2*)(P + (((long)(b * 4 + sl)) << 20) + ((long)j << 2));
    s0 += h2f(u.x & 0xffff); s1 += h2f(u.x >> 16);
    s2 += h2f(u.y & 0xffff); s3 += h2f(u.y >> 16);
  }
  const float fk = 4194304.0f / skr[(b << 10) + dk];
  const float4 fv = *(const float4*)&svr[(b << 10) + dv0];
  ((unsigned*)O)[i] = pk4e4(s0 * fk / fv.x, s1 * fk / fv.y,
                            s2 * fk / fv.z, s3 * fk / fv.w);
}

// ---------------------------------------------------------------------------
// split-K x4 reduce -> fp8 GT: GT8[b][i] = f8( sum / 32 )
// ---------------------------------------------------------------------------
__global__ __launch_bounds__(256) void red4g(
    const unsigned short* __restrict__ P, unsigned char* __restrict__ O)
{
  const int i = blockIdx.x * 256 + threadIdx.x;
  const int b = i >> 18;
  const int j = i & 262143;
  float s0 = 0, s1 = 0, s2 = 0, s3 = 0;
#pragma unroll
  for (int sl = 0; sl < 4; ++sl) {
    const uint2 u = *(const uint2*)(P + (((long)(b * 4 + sl)) << 20) + ((long)j << 2));
    s0 += h2f(u.x & 0xffff); s1 += h2f(u.x >> 16);
    s2 += h2f(u.y & 0xffff); s3 += h2f(u.y >> 16);
  }
  ((unsigned*)O)[i] = pk4e4(s0 * 0.03125f, s1 * 0.03125f,
                            s2 * 0.03125f, s3 * 0.03125f);
}

// ---------------------------------------------------------------------------
extern "C" void kernel_launch(void* const* d_in, const int* in_sizes, int n_in,
                              void* d_out, int out_size, void* d_ws, size_t ws_size,
                              hipStream_t stream) {
  const float* q  = (const float*)d_in[0];
  const float* k  = (const float*)d_in[1];
  const float* v  = (const float*)d_in[2];
  const float* Wq = (const float*)d_in[3];
  const float* bq = (const float*)d_in[4];
  const float* Wk = (const float*)d_in[5];
  const float* bk = (const float*)d_in[6];
  const float* Wv = (const float*)d_in[7];
  const float* bv = (const float*)d_in[8];
  const float* Wo = (const float*)d_in[9];
  const float* bo = (const float*)d_in[10];
  float* out = (float*)d_out;

  // workspace (~100 MB)
  char* p = (char*)d_ws;
  unsigned short* Part = (unsigned short*)p; p += 33554432;   // fp16 [16][2^20]
  unsigned short* WTb  = (unsigned short*)p; p += 8388608;    // 4x fp16 [1024][1024]
  unsigned short* WqT = WTb;
  unsigned short* WkT = WTb + 1L * 1024 * 1024;
  unsigned short* WvT = WTb + 2L * 1024 * 1024;
  unsigned short* WoT = WTb + 3L * 1024 * 1024;
  unsigned char* WoT8 = (unsigned char*)p;   p += 1048576;    // fp8 [1024][1024]
  unsigned char* Eq8  = (unsigned char*)p;   p += 16777216;   // fp8 [4][4096][1024]
  unsigned char* ETk8 = (unsigned char*)p;   p += 16777216;   // fp8 [4][1024][4096]
  unsigned char* ETv8 = (unsigned char*)p;   p += 16777216;
  unsigned char* Mh8  = (unsigned char*)p;   p += 4194304;    // fp8 [4][1024][1024]
  unsigned char* GT8  = (unsigned char*)p;   p += 4194304;    // fp8 [4][1024][1024]
  float* sqraw = (float*)p; p += 16384 * 4;   // raw row-sums of Eq
  float* skraw = (float*)p; p += 4096 * 4;    // raw col-sums of Ek
  float* svraw = (float*)p; p += 4096 * 4;    // raw col-sums of Ev

  const dim3 blk(256);
  const dim3 blk512(512);
  const long S22 = 4096L * 1024;   // 2^22
  const long S20 = 1024L * 1024;   // 2^20

  // zero the atomic sum accumulators (96 KB; graph-capturable)
  hipMemsetAsync(sqraw, 0, (16384 + 4096 + 4096) * sizeof(float), stream);

  // weights -> fp16 transposed; Wo also fp8*8
  w_trh4<<<dim3(16, 16, 4), blk, 0, stream>>>(Wq, Wk, Wv, Wo, WTb);
  wo8k<<<1024, blk, 0, stream>>>(WoT, WoT8);

  // ---- Q path: Eq8 = f8(exp(q@Wq+bq)/16) [row][dk]; sqraw = rowsums (raw)
  gemmt<0, 1, 3><<<512, blk512, 0, stream>>>(q, WqT, Eq8, bq, sqraw,
      1024, 1024, 1024, 4, 32, 1, S22, 0, S22);

  // ---- K path: ETk8[b][dk][l] = f8(exp^T/16); skraw = colsums (raw)
  gemmt<0, 1, 4><<<512, blk512, 0, stream>>>(k, WkT, ETk8, bk, skraw,
      1024, 1024, 1024, 4, 32, 1, S22, 0, S22);

  // ---- V path
  gemmt<0, 1, 4><<<512, blk512, 0, stream>>>(v, WvT, ETv8, bv, svraw,
      1024, 1024, 1024, 4, 32, 1, S22, 0, S22);

  // ---- M partials (fp8 GEMM, K=4096 split x4): P = ETk8 @ ETv8^T
  //      Mh8 = f8(red4(P) * 2^22 / (sk*sv))  (= M_true * 2^14)
  gemmt<1, 0, 2><<<512, blk512, 0, stream>>>(ETk8, ETv8, Part, nullptr, nullptr,
      1024, 1024, 4096, 4, 8, 4, S22, S22, S20);
  red4m<<<4096, blk, 0, stream>>>(Part, skraw, svraw, Mh8);

  // ---- GTraw (fp8 GEMM, K=1024 split x4): P = WoT8 @ Mh8^T
  //      GT8 = f8(red4(P)/32)  (= G_true * 2^12)
  gemmt<1, 0, 2><<<512, blk512, 0, stream>>>(WoT8, Mh8, Part, nullptr, nullptr,
      1024, 256, 1024, 4, 8, 4, 0, S20, S20);
  red4g<<<4096, blk, 0, stream>>>(Part, GT8);

  // ---- Out (fp8 GEMM): Out = (Eq8 @ GT8^T)/(256*sq) + bo
  gemmt<1, 0, 5><<<512, blk512, 0, stream>>>(Eq8, GT8, out, bo, sqraw,
      1024, 1024, 1024, 4, 32, 1, S22, S20, S22);

  (void)in_sizes; (void)n_in; (void)out_size; (void)ws_size;
}

// Round 16
// 262.964 us; speedup vs baseline: 1.1971x; 1.0680x over previous
//
#include <hip/hip_runtime.h>

typedef _Float16 f16x8 __attribute__((ext_vector_type(8)));
typedef float f32x4 __attribute__((ext_vector_type(4)));
typedef long lx2 __attribute__((ext_vector_type(2)));

__device__ __forceinline__ float h2f(unsigned short h) {
  return (float)__builtin_bit_cast(_Float16, h);
}
__device__ __forceinline__ unsigned short f2h(float f) {
  return __builtin_bit_cast(unsigned short, (_Float16)f);
}

#if __has_builtin(__builtin_amdgcn_cvt_pk_fp8_f32)
#define HW_FP8 1
#else
#define HW_FP8 0
#endif

// fp32 -> OCP e4m3fn (software fallback): RNE, saturating, subnormal-correct
__device__ __forceinline__ unsigned char f2e4_sw(float f) {
  unsigned short h = __builtin_bit_cast(unsigned short, (_Float16)f);
  unsigned s = (h >> 8) & 0x80u;
  unsigned ae = h & 0x7FFFu;
  if (ae >= 0x5F00u) return (unsigned char)(s | 0x7Eu);
  if (ae >= 0x2400u) {
    unsigned t = ae - 0x2000u;
    t = (t + 0x3Fu + ((t >> 7) & 1u)) >> 7;
    return (unsigned char)(s | t);
  }
  float v = (float)__builtin_bit_cast(_Float16, (unsigned short)ae) * 512.0f;
  int n = (int)rintf(v);
  return (unsigned char)(s | (unsigned)n);
}

// pack 2 fp8 into low 16 bits
__device__ __forceinline__ unsigned pk2e4(float a, float b) {
#if HW_FP8
  return (unsigned)__builtin_amdgcn_cvt_pk_fp8_f32(a, b, 0, false) & 0xFFFFu;
#else
  return (unsigned)f2e4_sw(a) | ((unsigned)f2e4_sw(b) << 8);
#endif
}
__device__ __forceinline__ unsigned pk4e4(float a, float b, float c, float d) {
#if HW_FP8
  int lo = __builtin_amdgcn_cvt_pk_fp8_f32(a, b, 0, false);
  return (unsigned)__builtin_amdgcn_cvt_pk_fp8_f32(c, d, lo, true);
#else
  return (unsigned)f2e4_sw(a) | ((unsigned)f2e4_sw(b) << 8) |
         ((unsigned)f2e4_sw(c) << 16) | ((unsigned)f2e4_sw(d) << 24);
#endif
}

__device__ __forceinline__ void gload_lds16(const void* g, void* l) {
  __builtin_amdgcn_global_load_lds(
      (const __attribute__((address_space(1))) void*)g,
      (__attribute__((address_space(3))) void*)l, 16, 0, 0);
}

// ---------------------------------------------------------------------------
// MERGED projection kernel: grid 1536 = 3 x 512; z (from XCD-swizzled id)
// selects {q,k,v}, weight slice WTb+z*2^20, output, bias, sum-target.
// Core = r13/r15 proven 128x256 fp16 GEMM (single 48KB LDS, 8 waves, plain
// syncthreads, XOR swizzle) + T14 fp32-A reg-prefetch + cvt.
// z==0: Eq8 = f8(exp(acc+bias)/16) [row][col] + fused row-sums (raw e).
// z>0 : ET8 = f8(exp/16) TRANSPOSED [col][row] packed 4B + fused col-sums.
// ---------------------------------------------------------------------------
__global__ __launch_bounds__(512, 4) void proj3(
    const float* __restrict__ A0, const float* __restrict__ A1,
    const float* __restrict__ A2, const unsigned short* __restrict__ WTb,
    const float* __restrict__ b0, const float* __restrict__ b1,
    const float* __restrict__ b2, unsigned char* __restrict__ C0,
    unsigned char* __restrict__ C1, unsigned char* __restrict__ C2,
    float* __restrict__ s0, float* __restrict__ s1, float* __restrict__ s2)
{
  __shared__ alignas(16) unsigned char smem[49152];  // A 16KB | B 32KB
  const int tid  = threadIdx.x;
  const int lane = tid & 63;
  const int wave = tid >> 6;
  const int waveM = wave >> 2;
  const int waveN = wave & 3;

  // bijective XCD swizzle over 1536 blocks (cpx = 192)
  const int wg = (int)blockIdx.x;
  const int w  = (wg & 7) * 192 + (wg >> 3);
  const int z  = w / 512;
  const int wl = w - z * 512;
  const int x  = wl & 3;
  const int rem = wl >> 2;
  const int y  = rem & 31;
  const int bz = rem >> 5;

  const float* Af = (z == 0) ? A0 : (z == 1) ? A1 : A2;
  const float* bi = (z == 0) ? b0 : (z == 1) ? b1 : b2;
  unsigned char* Cp = (z == 0) ? C0 : (z == 1) ? C1 : C2;
  float* sums = (z == 0) ? s0 : (z == 1) ? s1 : s2;

  const int m0 = y * 128, n0 = x * 256;

  // staging addresses (dst linear tid*16; src inverse-swizzled)
  const int srow = tid >> 3;
  const int scol = ((tid * 16) & 127) ^ ((srow & 7) << 4);   // fp16-bytes
  const char* BpR = (const char*)(WTb + (size_t)z * 1048576)
                    + (size_t)n0 * 2048 + (size_t)srow * 2048 + scol;
  const char* ApR32 = (const char*)Af + (size_t)bz * (4096L * 1024 * 4)
                      + (size_t)m0 * 4096 + (size_t)srow * 4096 + (size_t)scol * 2;
  const unsigned oA0 = (unsigned)tid * 16;

  // fragment byte offsets (kk=0); kk=1 is ^64
  int offA[4], offB[4];
  {
    const int q16 = (lane >> 4) << 4;
#pragma unroll
    for (int mi = 0; mi < 4; ++mi) {
      const int r = waveM * 64 + mi * 16 + (lane & 15);
      offA[mi] = r * 128 + (q16 ^ ((r & 7) << 4));
    }
#pragma unroll
    for (int ni = 0; ni < 4; ++ni) {
      const int r = waveN * 64 + ni * 16 + (lane & 15);
      offB[ni] = 16384 + r * 128 + (q16 ^ ((r & 7) << 4));
    }
  }

  f32x4 acc[4][4] = {};

  // T14 prefetch registers
  float4 pf0, pf1, pf2, pf3;
  {
    const char* sa = ApR32;
    const char* sb = sa + 4096 * 64;
    pf0 = *(const float4*)sa;  pf1 = *(const float4*)(sa + 16);
    pf2 = *(const float4*)sb;  pf3 = *(const float4*)(sb + 16);
  }

  for (int kt = 0; kt < 16; ++kt) {
    const size_t kb = (size_t)kt * 128;
    {
      unsigned short h0[8], h1[8];
      const float* fa0 = (const float*)&pf0; const float* fa1 = (const float*)&pf1;
      const float* fb0 = (const float*)&pf2; const float* fb1 = (const float*)&pf3;
#pragma unroll
      for (int e = 0; e < 4; ++e) {
        h0[e] = f2h(fa0[e]); h0[4 + e] = f2h(fa1[e]);
        h1[e] = f2h(fb0[e]); h1[4 + e] = f2h(fb1[e]);
      }
      *(uint4*)&smem[oA0]        = *(const uint4*)h0;
      *(uint4*)&smem[oA0 + 8192] = *(const uint4*)h1;
      if (kt + 1 < 16) {
        const char* sa = ApR32 + (size_t)(kt + 1) * 256;
        const char* sb = sa + 4096 * 64;
        pf0 = *(const float4*)sa;  pf1 = *(const float4*)(sa + 16);
        pf2 = *(const float4*)sb;  pf3 = *(const float4*)(sb + 16);
      }
    }
    gload_lds16(BpR + kb,                      smem + 16384 + oA0);
    gload_lds16(BpR + 2048 * 64 + kb,          smem + 16384 + oA0 + 8192);
    gload_lds16(BpR + 2048 * 128 + kb,         smem + 16384 + oA0 + 16384);
    gload_lds16(BpR + 2048 * 192 + kb,         smem + 16384 + oA0 + 24576);
    __syncthreads();
#pragma unroll
    for (int kk = 0; kk < 2; ++kk) {
      const int kx = kk << 6;
      f16x8 aF[4], bF[4];
#pragma unroll
      for (int mi = 0; mi < 4; ++mi) aF[mi] = *(const f16x8*)&smem[offA[mi] ^ kx];
#pragma unroll
      for (int ni = 0; ni < 4; ++ni) bF[ni] = *(const f16x8*)&smem[offB[ni] ^ kx];
#pragma unroll
      for (int mi = 0; mi < 4; ++mi)
#pragma unroll
        for (int ni = 0; ni < 4; ++ni)
          acc[mi][ni] = __builtin_amdgcn_mfma_f32_16x16x32_f16(aF[mi], bF[ni], acc[mi][ni], 0, 0, 0);
    }
    __syncthreads();
  }

  // ---- epilogue ----
  const int rb = (lane >> 4) * 4;
  const int cb_ = lane & 15;
  const long sC = 4096L * 1024;

  if (z == 0) {
    // fp8(e/16) store [row][col] + fused row-sums of raw e
#pragma unroll
    for (int m = 0; m < 4; ++m) {
      const int row0 = m0 + waveM * 64 + m * 16 + rb;
      float rs0 = 0, rs1 = 0, rs2 = 0, rs3 = 0;
#pragma unroll
      for (int n = 0; n < 4; ++n) {
        const int col = n0 + waveN * 64 + n * 16 + cb_;
        const float badd = bi[col];
        const float e0 = __expf(acc[m][n][0] + badd);
        const float e1 = __expf(acc[m][n][1] + badd);
        const float e2 = __expf(acc[m][n][2] + badd);
        const float e3 = __expf(acc[m][n][3] + badd);
        const unsigned p01 = pk2e4(e0 * 0.0625f, e1 * 0.0625f);
        const unsigned p23 = pk2e4(e2 * 0.0625f, e3 * 0.0625f);
        unsigned char* C8 = Cp + (long)bz * sC;
        C8[(size_t)(row0 + 0) * 1024 + col] = (unsigned char)(p01 & 0xff);
        C8[(size_t)(row0 + 1) * 1024 + col] = (unsigned char)((p01 >> 8) & 0xff);
        C8[(size_t)(row0 + 2) * 1024 + col] = (unsigned char)(p23 & 0xff);
        C8[(size_t)(row0 + 3) * 1024 + col] = (unsigned char)((p23 >> 8) & 0xff);
        rs0 += e0; rs1 += e1; rs2 += e2; rs3 += e3;
      }
#pragma unroll
      for (int off = 1; off <= 8; off <<= 1) {
        rs0 += __shfl_xor(rs0, off);
        rs1 += __shfl_xor(rs1, off);
        rs2 += __shfl_xor(rs2, off);
        rs3 += __shfl_xor(rs3, off);
      }
      if ((lane & 15) == 0) {
        float* s = sums + (size_t)bz * 4096 + row0;
        atomicAdd(s + 0, rs0);
        atomicAdd(s + 1, rs1);
        atomicAdd(s + 2, rs2);
        atomicAdd(s + 3, rs3);
      }
    }
  } else {
    // transposed fp8(e/16) store (packed 4B) + fused col-sums of raw e
    float cs[4] = {0.f, 0.f, 0.f, 0.f};
#pragma unroll
    for (int m = 0; m < 4; ++m) {
      const int row0 = m0 + waveM * 64 + m * 16 + rb;
#pragma unroll
      for (int n = 0; n < 4; ++n) {
        const int col = n0 + waveN * 64 + n * 16 + cb_;
        const float badd = bi[col];
        float ev[4];
        float ls = 0.f;
#pragma unroll
        for (int r = 0; r < 4; ++r) {
          ev[r] = __expf(acc[m][n][r] + badd);
          ls += ev[r];
        }
        cs[n] += ls;
        *(unsigned*)(Cp + (long)bz * sC + ((size_t)col << 12) + row0) =
            pk4e4(ev[0] * 0.0625f, ev[1] * 0.0625f, ev[2] * 0.0625f, ev[3] * 0.0625f);
      }
    }
#pragma unroll
    for (int n = 0; n < 4; ++n) {
      cs[n] += __shfl_xor(cs[n], 16);
      cs[n] += __shfl_xor(cs[n], 32);
    }
    if (lane < 16) {
#pragma unroll
      for (int n = 0; n < 4; ++n) {
        const int col = n0 + waveN * 64 + n * 16 + lane;
        atomicAdd(sums + ((size_t)bz << 10) + col, cs[n]);
      }
    }
  }
}

// ---------------------------------------------------------------------------
// fp8 GEMM, 128x256 tile, C = A @ Bt^T (e4m3 operands, BK=128, fp32 acc).
// Same proven core (single 48KB LDS, 8 waves, plain syncthreads, XOR swizzle,
// XCD-swizzled grid). Each 16B fragment feeds 2 fp8 MFMAs (consistent
// k-permutation across A/B => exact C).
// OUTMODE 2: fp16 split-K partial (slice zt)
//         5: fp32 acc/(256*sums[row]) + bias[col]
// ---------------------------------------------------------------------------
template <int OUTMODE>
__global__ __launch_bounds__(512, 4) void gemm8(
    const unsigned char* __restrict__ A, const unsigned char* __restrict__ Bt,
    void* __restrict__ Cv, const float* __restrict__ bias,
    const float* __restrict__ sums,
    int N, int K, int ldk, int gx, int gy, int nsplit,
    long sA, long sB, long sC)
{
  __shared__ alignas(16) unsigned char smem[49152];
  const int tid  = threadIdx.x;
  const int lane = tid & 63;
  const int wave = tid >> 6;
  const int waveM = wave >> 2;
  const int waveN = wave & 3;

  const int nwg = (int)gridDim.x;
  const int cpx = nwg >> 3;
  const int wg  = (int)blockIdx.x;
  const int w   = (wg & 7) * cpx + (wg >> 3);
  const int x   = w % gx;
  const int rem = w / gx;
  const int y   = rem % gy;
  const int zt  = rem / gy;
  const int bz  = zt / nsplit;
  const int sp  = zt % nsplit;

  const int m0 = y * 128, n0 = x * 256;
  const size_t ldkB = (size_t)ldk;
  const size_t ldkB64 = ldkB * 64, ldkB128 = ldkB * 128;

  const int srow = tid >> 3;
  const int scol = ((tid * 16) & 127) ^ ((srow & 7) << 4);
  const char* ApR;
  const char* BpR;
  {
    const char* Ab = (const char*)A + (long)bz * sA + (long)sp * K + (size_t)m0 * ldkB;
    const char* Bb = (const char*)Bt + (long)bz * sB + (long)sp * K + (size_t)n0 * ldkB;
    ApR = Ab + (size_t)srow * ldkB + scol;
    BpR = Bb + (size_t)srow * ldkB + scol;
  }
  const unsigned oA0 = (unsigned)tid * 16;

  int offA[4], offB[4];
  {
    const int q16 = (lane >> 4) << 4;
#pragma unroll
    for (int mi = 0; mi < 4; ++mi) {
      const int r = waveM * 64 + mi * 16 + (lane & 15);
      offA[mi] = r * 128 + (q16 ^ ((r & 7) << 4));
    }
#pragma unroll
    for (int ni = 0; ni < 4; ++ni) {
      const int r = waveN * 64 + ni * 16 + (lane & 15);
      offB[ni] = 16384 + r * 128 + (q16 ^ ((r & 7) << 4));
    }
  }

  f32x4 acc[4][4] = {};

  const int nk = K >> 7;
  for (int kt = 0; kt < nk; ++kt) {
    const size_t kb = (size_t)kt * 128;
    gload_lds16(ApR + kb,                     smem + oA0);
    gload_lds16(ApR + ldkB64 + kb,            smem + oA0 + 8192);
    gload_lds16(BpR + kb,                     smem + 16384 + oA0);
    gload_lds16(BpR + ldkB64 + kb,            smem + 16384 + oA0 + 8192);
    gload_lds16(BpR + ldkB128 + kb,           smem + 16384 + oA0 + 16384);
    gload_lds16(BpR + ldkB128 + ldkB64 + kb,  smem + 16384 + oA0 + 24576);
    __syncthreads();
#pragma unroll
    for (int kk = 0; kk < 2; ++kk) {
      const int kx = kk << 6;
      lx2 aF[4], bF[4];
#pragma unroll
      for (int mi = 0; mi < 4; ++mi) aF[mi] = *(const lx2*)&smem[offA[mi] ^ kx];
#pragma unroll
      for (int ni = 0; ni < 4; ++ni) bF[ni] = *(const lx2*)&smem[offB[ni] ^ kx];
#pragma unroll
      for (int h = 0; h < 2; ++h)
#pragma unroll
        for (int mi = 0; mi < 4; ++mi)
#pragma unroll
          for (int ni = 0; ni < 4; ++ni)
            acc[mi][ni] = __builtin_amdgcn_mfma_f32_16x16x32_fp8_fp8(
                aF[mi][h], bF[ni][h], acc[mi][ni], 0, 0, 0);
    }
    __syncthreads();
  }

  const int rb = (lane >> 4) * 4;
  const int cb_ = lane & 15;
  const long zout = (OUTMODE == 2) ? (long)zt : (long)bz;
#pragma unroll
  for (int m = 0; m < 4; ++m) {
    const int row0 = m0 + waveM * 64 + m * 16 + rb;
    float i0 = 0, i1 = 0, i2 = 0, i3 = 0;
    if (OUTMODE == 5) {
      const float4 s4 = *(const float4*)&sums[(size_t)zout * 4096 + row0];
      i0 = 1.0f / (256.0f * s4.x); i1 = 1.0f / (256.0f * s4.y);
      i2 = 1.0f / (256.0f * s4.z); i3 = 1.0f / (256.0f * s4.w);
    }
#pragma unroll
    for (int n = 0; n < 4; ++n) {
      const int col = n0 + waveN * 64 + n * 16 + cb_;
      if (OUTMODE == 2) {
#pragma unroll
        for (int r = 0; r < 4; ++r)
          ((unsigned short*)Cv)[zout * sC + (size_t)(row0 + r) * N + col] = f2h(acc[m][n][r]);
      } else {
        const float badd = bias[col];
        float* C32 = (float*)Cv;
        C32[zout * sC + (size_t)(row0 + 0) * N + col] = acc[m][n][0] * i0 + badd;
        C32[zout * sC + (size_t)(row0 + 1) * N + col] = acc[m][n][1] * i1 + badd;
        C32[zout * sC + (size_t)(row0 + 2) * N + col] = acc[m][n][2] * i2 + badd;
        C32[zout * sC + (size_t)(row0 + 3) * N + col] = acc[m][n][3] * i3 + badd;
      }
    }
  }
}

// ---------------------------------------------------------------------------
// Weight transpose + fp16 (4 weights, z selects): WT[z][c][r] = f16(W_z[r][c])
// z==3 additionally writes WoT8 = fp8(Wo^T * 8).
// ---------------------------------------------------------------------------
__global__ __launch_bounds__(256) void w_trh4(
    const float* __restrict__ W0, const float* __restrict__ W1,
    const float* __restrict__ W2, const float* __restrict__ W3,
    unsigned short* __restrict__ WTb, unsigned char* __restrict__ WoT8)
{
  __shared__ unsigned short tile[64][73];
  const int z = blockIdx.z;
  const float* W = (z == 0) ? W0 : (z == 1) ? W1 : (z == 2) ? W2 : W3;
  unsigned short* WT = WTb + (size_t)z * 1024 * 1024;
  const int c0 = blockIdx.x * 64;
  const int r0 = blockIdx.y * 64;
  const int tid = threadIdx.x;
  const int r = tid >> 2;
  const int cq = (tid & 3) * 16;
#pragma unroll
  for (int i = 0; i < 4; ++i) {
    const int c = cq + i * 4;
    const float4 v = *(const float4*)&W[(size_t)(r0 + r) * 1024 + c0 + c];
    tile[r][c + 0] = f2h(v.x);
    tile[r][c + 1] = f2h(v.y);
    tile[r][c + 2] = f2h(v.z);
    tile[r][c + 3] = f2h(v.w);
  }
  __syncthreads();
  const int c = tid >> 2;
  const int rq = (tid & 3) * 16;
  unsigned short outv[16];
#pragma unroll
  for (int j = 0; j < 16; ++j) outv[j] = tile[rq + j][c];
  unsigned short* Tb = WT + (size_t)(c0 + c) * 1024 + r0 + rq;
  ((uint4*)Tb)[0] = ((const uint4*)outv)[0];
  ((uint4*)Tb)[1] = ((const uint4*)outv)[1];
  if (z == 3) {
    unsigned u4[4];
#pragma unroll
    for (int j = 0; j < 4; ++j)
      u4[j] = pk4e4(h2f(outv[4 * j + 0]) * 8.f, h2f(outv[4 * j + 1]) * 8.f,
                    h2f(outv[4 * j + 2]) * 8.f, h2f(outv[4 * j + 3]) * 8.f);
    *(uint4*)(WoT8 + (size_t)(c0 + c) * 1024 + r0 + rq) = *(const uint4*)u4;
  }
}

// ---------------------------------------------------------------------------
// split-K x4 reduce of fp16 partials -> fp8 M with normalization:
// M8[b][dk][dv] = f8( sum * 2^22 / (skr[b][dk] * svr[b][dv]) )
// ---------------------------------------------------------------------------
__global__ __launch_bounds__(256) void red4m(
    const unsigned short* __restrict__ P, const float* __restrict__ skr,
    const float* __restrict__ svr, unsigned char* __restrict__ O)
{
  const int i = blockIdx.x * 256 + threadIdx.x;
  const int b = i >> 18;
  const int j = i & 262143;
  const int dk = j >> 8;
  const int dv0 = (j & 255) << 2;
  float s0 = 0, s1 = 0, s2 = 0, s3 = 0;
#pragma unroll
  for (int sl = 0; sl < 4; ++sl) {
    const uint2 u = *(const uint2*)(P + (((long)(b * 4 + sl)) << 20) + ((long)j << 2));
    s0 += h2f(u.x & 0xffff); s1 += h2f(u.x >> 16);
    s2 += h2f(u.y & 0xffff); s3 += h2f(u.y >> 16);
  }
  const float fk = 4194304.0f / skr[(b << 10) + dk];
  const float4 fv = *(const float4*)&svr[(b << 10) + dv0];
  ((unsigned*)O)[i] = pk4e4(s0 * fk / fv.x, s1 * fk / fv.y,
                            s2 * fk / fv.z, s3 * fk / fv.w);
}

// ---------------------------------------------------------------------------
// split-K x4 reduce -> fp8 GT: GT8[b][i] = f8( sum / 32 )
// ---------------------------------------------------------------------------
__global__ __launch_bounds__(256) void red4g(
    const unsigned short* __restrict__ P, unsigned char* __restrict__ O)
{
  const int i = blockIdx.x * 256 + threadIdx.x;
  const int b = i >> 18;
  const int j = i & 262143;
  float s0 = 0, s1 = 0, s2 = 0, s3 = 0;
#pragma unroll
  for (int sl = 0; sl < 4; ++sl) {
    const uint2 u = *(const uint2*)(P + (((long)(b * 4 + sl)) << 20) + ((long)j << 2));
    s0 += h2f(u.x & 0xffff); s1 += h2f(u.x >> 16);
    s2 += h2f(u.y & 0xffff); s3 += h2f(u.y >> 16);
  }
  ((unsigned*)O)[i] = pk4e4(s0 * 0.03125f, s1 * 0.03125f,
                            s2 * 0.03125f, s3 * 0.03125f);
}

// ---------------------------------------------------------------------------
extern "C" void kernel_launch(void* const* d_in, const int* in_sizes, int n_in,
                              void* d_out, int out_size, void* d_ws, size_t ws_size,
                              hipStream_t stream) {
  const float* q  = (const float*)d_in[0];
  const float* k  = (const float*)d_in[1];
  const float* v  = (const float*)d_in[2];
  const float* Wq = (const float*)d_in[3];
  const float* bq = (const float*)d_in[4];
  const float* Wk = (const float*)d_in[5];
  const float* bk = (const float*)d_in[6];
  const float* Wv = (const float*)d_in[7];
  const float* bv = (const float*)d_in[8];
  const float* Wo = (const float*)d_in[9];
  const float* bo = (const float*)d_in[10];
  float* out = (float*)d_out;

  // workspace (~100 MB)
  char* p = (char*)d_ws;
  unsigned short* Part = (unsigned short*)p; p += 33554432;   // fp16 [16][2^20]
  unsigned short* WTb  = (unsigned short*)p; p += 8388608;    // 4x fp16 [1024][1024]
  unsigned char* WoT8 = (unsigned char*)p;   p += 1048576;    // fp8 [1024][1024]
  unsigned char* Eq8  = (unsigned char*)p;   p += 16777216;   // fp8 [4][4096][1024]
  unsigned char* ETk8 = (unsigned char*)p;   p += 16777216;   // fp8 [4][1024][4096]
  unsigned char* ETv8 = (unsigned char*)p;   p += 16777216;
  unsigned char* Mh8  = (unsigned char*)p;   p += 4194304;    // fp8 [4][1024][1024]
  unsigned char* GT8  = (unsigned char*)p;   p += 4194304;    // fp8 [4][1024][1024]
  float* sqraw = (float*)p; p += 16384 * 4;   // raw row-sums of Eq
  float* skraw = (float*)p; p += 4096 * 4;    // raw col-sums of Ek
  float* svraw = (float*)p; p += 4096 * 4;    // raw col-sums of Ev

  const dim3 blk(256);
  const dim3 blk512(512);
  const long S22 = 4096L * 1024;
  const long S20 = 1024L * 1024;

  // zero the atomic sum accumulators (96 KB; graph-capturable)
  hipMemsetAsync(sqraw, 0, (16384 + 4096 + 4096) * sizeof(float), stream);

  // weights -> fp16 transposed (+ Wo fp8*8 fused)
  w_trh4<<<dim3(16, 16, 4), blk, 0, stream>>>(Wq, Wk, Wv, Wo, WTb, WoT8);

  // ---- merged projections: Eq8 / ETk8 / ETv8 + fused raw sums
  proj3<<<1536, blk512, 0, stream>>>(q, k, v, WTb, bq, bk, bv,
                                     Eq8, ETk8, ETv8, sqraw, skraw, svraw);

  // ---- M partials (fp8 GEMM, K=4096 split x4): P = ETk8 @ ETv8^T
  //      Mh8 = f8(red4(P) * 2^22 / (sk*sv))  (= M_true * 2^14)
  gemm8<2><<<512, blk512, 0, stream>>>(ETk8, ETv8, Part, nullptr, nullptr,
      1024, 1024, 4096, 4, 8, 4, S22, S22, S20);
  red4m<<<4096, blk, 0, stream>>>(Part, skraw, svraw, Mh8);

  // ---- GTraw (fp8 GEMM, K=1024 split x4): P = WoT8 @ Mh8^T
  //      GT8 = f8(red4(P)/32)  (= G_true * 2^12)
  gemm8<2><<<512, blk512, 0, stream>>>(WoT8, Mh8, Part, nullptr, nullptr,
      1024, 256, 1024, 4, 8, 4, 0, S20, S20);
  red4g<<<4096, blk, 0, stream>>>(Part, GT8);

  // ---- Out (fp8 GEMM): Out = (Eq8 @ GT8^T)/(256*sq) + bo
  gemm8<5><<<512, blk512, 0, stream>>>(Eq8, GT8, out, bo, sqraw,
      1024, 1024, 1024, 4, 32, 1, S22, S20, S22);

  (void)in_sizes; (void)n_in; (void)out_size; (void)ws_size;
}